// Round 6
// baseline (58.526 us; speedup 1.0000x reference)
//
#include <hip/hip_runtime.h>
#include <hip/hip_bf16.h>
#include <type_traits>

typedef __attribute__((ext_vector_type(4))) float f32x4;
typedef __attribute__((ext_vector_type(8))) short bf16x8;

template <int V> using ic = std::integral_constant<int, V>;

static constexpr int B_   = 2048;
static constexpr int IN_  = 1024;
static constexpr int HID_ = 2048;
static constexpr int NB_  = 8;
static constexpr int BS_  = 256;   // block size
static constexpr int G3_  = 768;   // 3*BS_

// fp32 -> bf16 RNE (scalar; compiler may fuse pairs to v_cvt_pk_bf16_f32)
__device__ __forceinline__ unsigned short f2bf(float f) {
  unsigned u = __builtin_bit_cast(unsigned, f);
  u = (u + 0x7FFFu + ((u >> 16) & 1u)) >> 16;
  return (unsigned short)u;
}

// ---------- fused block-GRU MFMA kernel, conversion fused into staging ----------
// Tile: 128 batch rows x 64 out-cols (192 gate cols); 4 waves (2x2).
// Accumulators: [0]=r (K=1280 combined), [1]=z (combined), [2]=i_n, [3]=h_n.
// LDS: 2 buffers x 40KB { A [128][64]bf16 @0, W [192][64]bf16 @16384 },
// XOR-swizzled phys = logical ^ ((row&7)<<4). Staging is reg-mediated:
// buffer_load fp32 (issued early) -> f2bf -> ds_write_b128 to the OTHER buffer
// while MFMAs read the current one => ONE __syncthreads per K-step, no cvt
// pre-kernel, no asm waitcnts (compiler inserts counted vmcnt before first use).
// Staging batches <=32 VGPR in flight: A(4 passes), W(3), W(3).
__global__ __launch_bounds__(256, 2) void gru_mfma(
    const float* __restrict__ xf,     // [2048][1024]
    const float* __restrict__ hf,     // [2048][2048]
    const float* __restrict__ Wih,    // [8][768][1024]
    const float* __restrict__ Whh,    // [8][768][256]
    const float* __restrict__ b_ih,   // [8][768]
    const float* __restrict__ b_hh,   // [8][768]
    float* __restrict__ out)          // [2048][2048]
{
  __shared__ __align__(16) char lds[2][40960];

  const int t    = threadIdx.x;
  const int lane = t & 63;
  const int wid  = t >> 6;
  const int wm   = wid >> 1;     // wave row (0..1) -> 64-row half
  const int wn   = wid & 1;      // wave col (0..1) -> 32-col half

  // Bijective XCD swizzle: nwg=512 = 8 XCDs x 64 -> each XCD owns one GRU block n.
  const int bid = blockIdx.x;
  const int swz = (bid & 7) * 64 + (bid >> 3);
  const int mrow0 = (swz & 15) * 128;
  const int ct    = swz >> 4;
  const int n     = ct >> 2;          // GRU block index
  const int s0    = (ct & 3) * 64;    // col offset within block

  // Staging pass p writes phys LDS offset op = p*4096 + t*16 (region-local);
  // the element that belongs there is logical ol = op ^ (((op>>7)&7)<<4)
  // (involution on byte bits [6:4]; row bits untouched).
  int arow[4], acol[4];
#pragma unroll
  for (int p = 0; p < 4; ++p) {
    int op = p * 4096 + t * 16;
    int ol = op ^ (((op >> 7) & 7) << 4);
    arow[p] = ol >> 7;            // 0..127
    acol[p] = (ol & 127) >> 1;    // element offset (multiple of 8)
  }
  int wgrow[6], wcol[6];
#pragma unroll
  for (int q = 0; q < 6; ++q) {
    int op = q * 4096 + t * 16;
    int ol = op ^ (((op >> 7) & 7) << 4);
    int wr = ol >> 7;             // 0..191
    wgrow[q] = n * G3_ + (wr >> 6) * BS_ + s0 + (wr & 63);  // global W row
    wcol[q]  = (ol & 127) >> 1;
  }

  f32x4 acc[4][4][2] = {};   // [set][mi][ni]
  float4 sa[4][2];           // A staging regs (32 VGPR)
  float4 sw[3][2];           // W staging regs (24 VGPR)

  auto issueA = [&](int t2) {
#pragma unroll
    for (int p = 0; p < 4; ++p) {
      const float* src = (t2 < 16)
        ? xf + (size_t)(mrow0 + arow[p]) * IN_  + t2 * 64 + acol[p]
        : hf + (size_t)(mrow0 + arow[p]) * HID_ + n * BS_ + (t2 - 16) * 64 + acol[p];
      sa[p][0] = *reinterpret_cast<const float4*>(src);
      sa[p][1] = *reinterpret_cast<const float4*>(src + 4);
    }
  };
  auto issueW = [&](int t2, int q0) {
#pragma unroll
    for (int j = 0; j < 3; ++j) {
      const int q = q0 + j;
      const float* src = (t2 < 16)
        ? Wih + (size_t)wgrow[q] * IN_ + t2 * 64 + wcol[q]
        : Whh + (size_t)wgrow[q] * BS_ + (t2 - 16) * 64 + wcol[q];
      sw[j][0] = *reinterpret_cast<const float4*>(src);
      sw[j][1] = *reinterpret_cast<const float4*>(src + 4);
    }
  };
  auto pack = [](const float4 (&v)[2]) {
    union { bf16x8 b; unsigned short s[8]; } u;
    u.s[0] = f2bf(v[0].x); u.s[1] = f2bf(v[0].y);
    u.s[2] = f2bf(v[0].z); u.s[3] = f2bf(v[0].w);
    u.s[4] = f2bf(v[1].x); u.s[5] = f2bf(v[1].y);
    u.s[6] = f2bf(v[1].z); u.s[7] = f2bf(v[1].w);
    return u.b;
  };
  auto writeA = [&](char* buf) {
#pragma unroll
    for (int p = 0; p < 4; ++p)
      *reinterpret_cast<bf16x8*>(buf + p * 4096 + t * 16) = pack(sa[p]);
  };
  auto writeW = [&](char* buf, int q0) {
#pragma unroll
    for (int j = 0; j < 3; ++j)
      *reinterpret_cast<bf16x8*>(buf + 16384 + (q0 + j) * 4096 + t * 16) = pack(sw[j]);
  };

  auto loadA = [&](const char* buf, bf16x8 (&af)[2][4]) {
#pragma unroll
    for (int ksub = 0; ksub < 2; ++ksub)
#pragma unroll
      for (int mi = 0; mi < 4; ++mi) {
        int ar  = wm * 64 + mi * 16 + (lane & 15);
        int off = ar * 128 + ksub * 64 + ((lane >> 4) * 16);
        off ^= (ar & 7) << 4;
        af[ksub][mi] = *reinterpret_cast<const bf16x8*>(buf + off);
      }
  };
  auto loadW = [&](const char* buf, int g, bf16x8 (&wf)[2][2]) {
#pragma unroll
    for (int ksub = 0; ksub < 2; ++ksub)
#pragma unroll
      for (int ni = 0; ni < 2; ++ni) {
        int wr  = g * 64 + wn * 32 + ni * 16 + (lane & 15);
        int off = wr * 128 + ksub * 64 + ((lane >> 4) * 16);
        off ^= (wr & 7) << 4;
        wf[ksub][ni] = *reinterpret_cast<const bf16x8*>(buf + 16384 + off);
      }
  };
  auto mfmaSet = [&](auto setc, bf16x8 (&af)[2][4], bf16x8 (&wf)[2][2]) {
    constexpr int set = decltype(setc)::value;
#pragma unroll
    for (int ksub = 0; ksub < 2; ++ksub)
#pragma unroll
      for (int mi = 0; mi < 4; ++mi)
#pragma unroll
        for (int ni = 0; ni < 2; ++ni)
          acc[set][mi][ni] = __builtin_amdgcn_mfma_f32_16x16x32_bf16(
              af[ksub][mi], wf[ksub][ni], acc[set][mi][ni], 0, 0, 0);
  };

  // ---- prologue: stage tile 0 into buf0 ----
  issueA(0);
  issueW(0, 0);
  writeA((char*)lds[0]);
  writeW((char*)lds[0], 0);
  issueW(0, 3);
  writeW((char*)lds[0], 3);
  __syncthreads();

  // ---- 20 K-steps (16 input + 4 hidden), fully unrolled, ONE barrier each ----
#pragma unroll
  for (int tt = 0; tt < 20; ++tt) {
    char* cur = (char*)lds[tt & 1];
    char* oth = (char*)lds[(tt & 1) ^ 1];
    bf16x8 af[2][4], wf[2][2];

    if (tt < 19) issueA(tt + 1);            // T14 issue-early
    loadA(cur, af);
    loadW(cur, 0, wf);
    mfmaSet(ic<0>{}, af, wf);
    if (tt < 19) { writeA(oth); issueW(tt + 1, 0); }
    loadW(cur, 1, wf);
    mfmaSet(ic<1>{}, af, wf);
    if (tt < 19) { writeW(oth, 0); issueW(tt + 1, 3); }
    loadW(cur, 2, wf);
    if (tt < 16) mfmaSet(ic<2>{}, af, wf);
    else         mfmaSet(ic<3>{}, af, wf);
    if (tt < 19) writeW(oth, 3);
    __syncthreads();   // writes to oth visible; reads of cur retired
  }

  // ---- epilogue: gates + output ----
#pragma unroll
  for (int ni = 0; ni < 2; ++ni) {
    int scol = s0 + wn * 32 + ni * 16 + (lane & 15);
    float br_i = b_ih[n * G3_ + 0 * BS_ + scol];
    float bz_i = b_ih[n * G3_ + 1 * BS_ + scol];
    float bn_i = b_ih[n * G3_ + 2 * BS_ + scol];
    float br_h = b_hh[n * G3_ + 0 * BS_ + scol];
    float bz_h = b_hh[n * G3_ + 1 * BS_ + scol];
    float bn_h = b_hh[n * G3_ + 2 * BS_ + scol];
    int gcol = n * BS_ + scol;
#pragma unroll
    for (int mi = 0; mi < 4; ++mi) {
#pragma unroll
      for (int i = 0; i < 4; ++i) {
        int row = mrow0 + wm * 64 + mi * 16 + (lane >> 4) * 4 + i;  // C/D: col=lane&15, row=(lane>>4)*4+reg
        float hprev = hf[(size_t)row * HID_ + gcol];
        float rr = acc[0][mi][ni][i] + br_i + br_h;
        float zz = acc[1][mi][ni][i] + bz_i + bz_h;
        float r  = 1.f / (1.f + __expf(-rr));
        float z  = 1.f / (1.f + __expf(-zz));
        float ng = tanhf(acc[2][mi][ni][i] + bn_i + r * (acc[3][mi][ni][i] + bn_h));
        out[(size_t)row * HID_ + gcol] = (1.f - z) * ng + z * hprev;
      }
    }
  }
}

extern "C" void kernel_launch(void* const* d_in, const int* in_sizes, int n_in,
                              void* d_out, int out_size, void* d_ws, size_t ws_size,
                              hipStream_t stream) {
  const float* x   = (const float*)d_in[0];
  const float* h   = (const float*)d_in[1];
  const float* Wih = (const float*)d_in[2];
  const float* Whh = (const float*)d_in[3];
  const float* bih = (const float*)d_in[4];
  const float* bhh = (const float*)d_in[5];
  float* out = (float*)d_out;
  (void)d_ws; (void)ws_size;

  gru_mfma<<<512, 256, 0, stream>>>(x, h, Wih, Whh, bih, bhh, out);
}

// Round 7
// 55.600 us; speedup vs baseline: 1.0526x; 1.0526x over previous
//
#include <hip/hip_runtime.h>
#include <hip/hip_bf16.h>
#include <type_traits>

typedef __attribute__((ext_vector_type(4))) float f32x4;
typedef __attribute__((ext_vector_type(8))) short bf16x8;

template <int V> using ic = std::integral_constant<int, V>;

static constexpr int B_   = 2048;
static constexpr int IN_  = 1024;
static constexpr int HID_ = 2048;
static constexpr int NB_  = 8;
static constexpr int BS_  = 256;   // block size
static constexpr int G3_  = 768;   // 3*BS_

// packed fp32x2 -> bf16x2 RNE, single VALU op (no builtin on gfx950 - T12)
__device__ __forceinline__ unsigned cvtpk(float lo, float hi) {
  unsigned r;
  asm("v_cvt_pk_bf16_f32 %0, %1, %2" : "=v"(r) : "v"(lo), "v"(hi));
  return r;
}

// ---------- fused block-GRU MFMA kernel, fp32->bf16 fused into staging ----------
// Tile: 128 batch rows x 64 out-cols (192 gate cols); 4 waves (2x2), wave 64x32.
// Accumulators: [0]=r (K=1280 combined), [1]=z (combined), [2]=i_n, [3]=h_n.
// LDS: 2 buffers x 40KB { A [128][64]bf16 @0, W [192][64]bf16 @16384 },
// XOR-swizzled phys = logical ^ ((row&7)<<4). Staging is reg-mediated from the
// ORIGINAL fp32 tensors (no cvt pre-kernel): buffer_load fp32 -> v_cvt_pk_bf16_f32
// -> ds_write_b128 into the other buffer. T14 issue-early/write-late in 2 batches:
//   issue b1(A+Wq0-1) | g0 MFMAs | write b1; issue b2(Wq2-5) | g1,g2 MFMAs |
//   write b2 | one __syncthreads.
// sched_barrier(0) pins the issue/write split; compiler inserts counted vmcnt.
__global__ __launch_bounds__(256, 2) void gru_mfma(
    const float* __restrict__ xf,     // [2048][1024]
    const float* __restrict__ hf,     // [2048][2048]
    const float* __restrict__ Wih,    // [8][768][1024]
    const float* __restrict__ Whh,    // [8][768][256]
    const float* __restrict__ b_ih,   // [8][768]
    const float* __restrict__ b_hh,   // [8][768]
    float* __restrict__ out)          // [2048][2048]
{
  __shared__ __align__(16) char lds[2][40960];

  const int t    = threadIdx.x;
  const int lane = t & 63;
  const int wid  = t >> 6;
  const int wm   = wid >> 1;     // wave row (0..1) -> 64-row half
  const int wn   = wid & 1;      // wave col (0..1) -> 32-col half

  // Bijective XCD swizzle: nwg=512 = 8 XCDs x 64 -> each XCD owns one GRU block n
  // (its W panel = 768x1280 fp32 = 3.9 MB, L2-resident per XCD).
  const int bid = blockIdx.x;
  const int swz = (bid & 7) * 64 + (bid >> 3);
  const int mrow0 = (swz & 15) * 128;
  const int ct    = swz >> 4;
  const int n     = ct >> 2;          // GRU block index
  const int s0    = (ct & 3) * 64;    // col offset within block

  // Staging pass p writes phys LDS offset op = p*4096 + t*16 (region-local);
  // logical ol = op ^ (((op>>7)&7)<<4) (involution on byte bits [6:4]).
  int arow[4], acol[4];
#pragma unroll
  for (int p = 0; p < 4; ++p) {
    int op = p * 4096 + t * 16;
    int ol = op ^ (((op >> 7) & 7) << 4);
    arow[p] = ol >> 7;            // 0..127
    acol[p] = (ol & 127) >> 1;    // element (fp32/bf16) offset, multiple of 8
  }
  int wgrow[6], wcol[6];
#pragma unroll
  for (int q = 0; q < 6; ++q) {
    int op = q * 4096 + t * 16;
    int ol = op ^ (((op >> 7) & 7) << 4);
    int wr = ol >> 7;             // 0..191
    wgrow[q] = n * G3_ + (wr >> 6) * BS_ + s0 + (wr & 63);  // global W row
    wcol[q]  = (ol & 127) >> 1;
  }

  f32x4 acc[4][4][2] = {};   // [set][mi][ni]
  float4 s1[6][2];           // batch1: A passes 0-3 + W passes 0-1 (48 VGPR)
  float4 s2[4][2];           // batch2: W passes 2-5 (32 VGPR)

  auto issueB1 = [&](int t2) {
#pragma unroll
    for (int p = 0; p < 4; ++p) {
      const float* src = (t2 < 16)
        ? xf + (size_t)(mrow0 + arow[p]) * IN_  + t2 * 64 + acol[p]
        : hf + (size_t)(mrow0 + arow[p]) * HID_ + n * BS_ + (t2 - 16) * 64 + acol[p];
      s1[p][0] = *reinterpret_cast<const float4*>(src);
      s1[p][1] = *reinterpret_cast<const float4*>(src + 4);
    }
#pragma unroll
    for (int q = 0; q < 2; ++q) {
      const float* src = (t2 < 16)
        ? Wih + (size_t)wgrow[q] * IN_ + t2 * 64 + wcol[q]
        : Whh + (size_t)wgrow[q] * BS_ + (t2 - 16) * 64 + wcol[q];
      s1[4 + q][0] = *reinterpret_cast<const float4*>(src);
      s1[4 + q][1] = *reinterpret_cast<const float4*>(src + 4);
    }
  };
  auto issueB2 = [&](int t2) {
#pragma unroll
    for (int j = 0; j < 4; ++j) {
      const int q = 2 + j;
      const float* src = (t2 < 16)
        ? Wih + (size_t)wgrow[q] * IN_ + t2 * 64 + wcol[q]
        : Whh + (size_t)wgrow[q] * BS_ + (t2 - 16) * 64 + wcol[q];
      s2[j][0] = *reinterpret_cast<const float4*>(src);
      s2[j][1] = *reinterpret_cast<const float4*>(src + 4);
    }
  };
  auto pack8 = [&](const float4& a, const float4& b) {
    union { unsigned u[4]; bf16x8 v; } r;
    r.u[0] = cvtpk(a.x, a.y); r.u[1] = cvtpk(a.z, a.w);
    r.u[2] = cvtpk(b.x, b.y); r.u[3] = cvtpk(b.z, b.w);
    return r.v;
  };
  auto writeB1 = [&](char* buf) {
#pragma unroll
    for (int p = 0; p < 4; ++p)
      *reinterpret_cast<bf16x8*>(buf + p * 4096 + t * 16) = pack8(s1[p][0], s1[p][1]);
#pragma unroll
    for (int q = 0; q < 2; ++q)
      *reinterpret_cast<bf16x8*>(buf + 16384 + q * 4096 + t * 16) = pack8(s1[4 + q][0], s1[4 + q][1]);
  };
  auto writeB2 = [&](char* buf) {
#pragma unroll
    for (int j = 0; j < 4; ++j)
      *reinterpret_cast<bf16x8*>(buf + 16384 + (2 + j) * 4096 + t * 16) = pack8(s2[j][0], s2[j][1]);
  };

  auto loadA = [&](const char* buf, bf16x8 (&af)[2][4]) {
#pragma unroll
    for (int ksub = 0; ksub < 2; ++ksub)
#pragma unroll
      for (int mi = 0; mi < 4; ++mi) {
        int ar  = wm * 64 + mi * 16 + (lane & 15);
        int off = ar * 128 + ksub * 64 + ((lane >> 4) * 16);
        off ^= (ar & 7) << 4;
        af[ksub][mi] = *reinterpret_cast<const bf16x8*>(buf + off);
      }
  };
  auto loadW = [&](const char* buf, int g, bf16x8 (&wf)[2][2]) {
#pragma unroll
    for (int ksub = 0; ksub < 2; ++ksub)
#pragma unroll
      for (int ni = 0; ni < 2; ++ni) {
        int wr  = g * 64 + wn * 32 + ni * 16 + (lane & 15);
        int off = wr * 128 + ksub * 64 + ((lane >> 4) * 16);
        off ^= (wr & 7) << 4;
        wf[ksub][ni] = *reinterpret_cast<const bf16x8*>(buf + 16384 + off);
      }
  };
  auto mfmaSet = [&](auto setc, bf16x8 (&af)[2][4], bf16x8 (&wf)[2][2]) {
    constexpr int set = decltype(setc)::value;
    __builtin_amdgcn_s_setprio(1);
#pragma unroll
    for (int ksub = 0; ksub < 2; ++ksub)
#pragma unroll
      for (int mi = 0; mi < 4; ++mi)
#pragma unroll
        for (int ni = 0; ni < 2; ++ni)
          acc[set][mi][ni] = __builtin_amdgcn_mfma_f32_16x16x32_bf16(
              af[ksub][mi], wf[ksub][ni], acc[set][mi][ni], 0, 0, 0);
    __builtin_amdgcn_s_setprio(0);
  };

  // ---- prologue: stage tile 0 into buf0 ----
  issueB1(0);
  writeB1((char*)lds[0]);
  issueB2(0);
  writeB2((char*)lds[0]);
  __syncthreads();

  // ---- 20 K-steps (16 input + 4 hidden), fully unrolled, ONE barrier each ----
#pragma unroll
  for (int tt = 0; tt < 20; ++tt) {
    char* cur = (char*)lds[tt & 1];
    char* oth = (char*)lds[(tt & 1) ^ 1];
    bf16x8 af[2][4], wf[2][2];

    if (tt < 19) issueB1(tt + 1);           // T14: issue early
    __builtin_amdgcn_sched_barrier(0);      // loads stay above the MFMA phase
    loadA(cur, af);
    loadW(cur, 0, wf);
    mfmaSet(ic<0>{}, af, wf);
    __builtin_amdgcn_sched_barrier(0);      // write-late boundary
    if (tt < 19) { writeB1(oth); issueB2(tt + 1); }
    __builtin_amdgcn_sched_barrier(0);
    loadW(cur, 1, wf);
    mfmaSet(ic<1>{}, af, wf);
    loadW(cur, 2, wf);
    if (tt < 16) mfmaSet(ic<2>{}, af, wf);
    else         mfmaSet(ic<3>{}, af, wf);
    __builtin_amdgcn_sched_barrier(0);
    if (tt < 19) writeB2(oth);
    __syncthreads();   // writes to oth visible; reads of cur retired
  }

  // ---- epilogue: gates + output ----
#pragma unroll
  for (int ni = 0; ni < 2; ++ni) {
    int scol = s0 + wn * 32 + ni * 16 + (lane & 15);
    float br_i = b_ih[n * G3_ + 0 * BS_ + scol];
    float bz_i = b_ih[n * G3_ + 1 * BS_ + scol];
    float bn_i = b_ih[n * G3_ + 2 * BS_ + scol];
    float br_h = b_hh[n * G3_ + 0 * BS_ + scol];
    float bz_h = b_hh[n * G3_ + 1 * BS_ + scol];
    float bn_h = b_hh[n * G3_ + 2 * BS_ + scol];
    int gcol = n * BS_ + scol;
#pragma unroll
    for (int mi = 0; mi < 4; ++mi) {
#pragma unroll
      for (int i = 0; i < 4; ++i) {
        int row = mrow0 + wm * 64 + mi * 16 + (lane >> 4) * 4 + i;  // C/D: col=lane&15, row=(lane>>4)*4+reg
        float hprev = hf[(size_t)row * HID_ + gcol];
        float rr = acc[0][mi][ni][i] + br_i + br_h;
        float zz = acc[1][mi][ni][i] + bz_i + bz_h;
        float r  = 1.f / (1.f + __expf(-rr));
        float z  = 1.f / (1.f + __expf(-zz));
        float ng = tanhf(acc[2][mi][ni][i] + bn_i + r * (acc[3][mi][ni][i] + bn_h));
        out[(size_t)row * HID_ + gcol] = (1.f - z) * ng + z * hprev;
      }
    }
  }
}

extern "C" void kernel_launch(void* const* d_in, const int* in_sizes, int n_in,
                              void* d_out, int out_size, void* d_ws, size_t ws_size,
                              hipStream_t stream) {
  const float* x   = (const float*)d_in[0];
  const float* h   = (const float*)d_in[1];
  const float* Wih = (const float*)d_in[2];
  const float* Whh = (const float*)d_in[3];
  const float* bih = (const float*)d_in[4];
  const float* bhh = (const float*)d_in[5];
  float* out = (float*)d_out;
  (void)d_ws; (void)ws_size;

  gru_mfma<<<512, 256, 0, stream>>>(x, h, Wih, Whh, bih, bhh, out);
}

// Round 8
// 53.734 us; speedup vs baseline: 1.0892x; 1.0347x over previous
//
#include <hip/hip_runtime.h>
#include <hip/hip_bf16.h>
#include <type_traits>

typedef __attribute__((ext_vector_type(4))) float f32x4;
typedef __attribute__((ext_vector_type(8))) short bf16x8;

template <int V> using ic = std::integral_constant<int, V>;

static constexpr int B_   = 2048;
static constexpr int IN_  = 1024;
static constexpr int HID_ = 2048;
static constexpr int NB_  = 8;
static constexpr int BS_  = 256;   // block size
static constexpr int G3_  = 768;   // 3*BS_

// packed fp32x2 -> bf16x2 RNE, single VALU op (no builtin on gfx950 - T12)
__device__ __forceinline__ unsigned cvtpk(float lo, float hi) {
  unsigned r;
  asm("v_cvt_pk_bf16_f32 %0, %1, %2" : "=v"(r) : "v"(lo), "v"(hi));
  return r;
}

// ---------- fused block-GRU MFMA kernel, fp32->bf16 fused into staging ----------
// Tile: 128 batch rows x 64 out-cols (192 gate cols); 4 waves (2x2), wave 64x32.
// Accumulators: [0]=r (K=1280 combined), [1]=z (combined), [2]=i_n, [3]=h_n.
// LDS: 2 buffers x 40KB { A [128][64]bf16 @0, W [192][64]bf16 @16384 },
// XOR-swizzled phys = logical ^ ((row&7)<<4). Staging reg-mediated from the
// ORIGINAL fp32 tensors (no cvt pre-kernel): global fp32 load -> v_cvt_pk_bf16_f32
// -> ds_write_b128 into the other buffer.
// ROUND-8 FIX vs round 7: staging uses ONE 32-VGPR buffer in 3 batches
// (A[0..3] | W[0..2] | W[3..5]), each issued one MFMA gate-phase before its
// write -> in-flight regs 80->32, no spill; gap ~16 MFMAs covers L2 latency.
__global__ __launch_bounds__(256, 2) void gru_mfma(
    const float* __restrict__ xf,     // [2048][1024]
    const float* __restrict__ hf,     // [2048][2048]
    const float* __restrict__ Wih,    // [8][768][1024]
    const float* __restrict__ Whh,    // [8][768][256]
    const float* __restrict__ b_ih,   // [8][768]
    const float* __restrict__ b_hh,   // [8][768]
    float* __restrict__ out)          // [2048][2048]
{
  __shared__ __align__(16) char lds[2][40960];

  const int t    = threadIdx.x;
  const int lane = t & 63;
  const int wid  = t >> 6;
  const int wm   = wid >> 1;     // wave row (0..1) -> 64-row half
  const int wn   = wid & 1;      // wave col (0..1) -> 32-col half

  // Bijective XCD swizzle: nwg=512 = 8 XCDs x 64 -> each XCD owns one GRU block n
  // (its W panel = 768x1280 fp32 = 3.9 MB, L2-resident per XCD).
  const int bid = blockIdx.x;
  const int swz = (bid & 7) * 64 + (bid >> 3);
  const int mrow0 = (swz & 15) * 128;
  const int ct    = swz >> 4;
  const int n     = ct >> 2;          // GRU block index
  const int s0    = (ct & 3) * 64;    // col offset within block

  // Staging pass p writes phys LDS offset op = p*4096 + t*16 (region-local);
  // logical ol = op ^ (((op>>7)&7)<<4) (involution on byte bits [6:4]).
  int arow[4], acol[4];
#pragma unroll
  for (int p = 0; p < 4; ++p) {
    int op = p * 4096 + t * 16;
    int ol = op ^ (((op >> 7) & 7) << 4);
    arow[p] = ol >> 7;            // 0..127
    acol[p] = (ol & 127) >> 1;    // element offset, multiple of 8
  }
  int wgrow[6], wcol[6];
#pragma unroll
  for (int q = 0; q < 6; ++q) {
    int op = q * 4096 + t * 16;
    int ol = op ^ (((op >> 7) & 7) << 4);
    int wr = ol >> 7;             // 0..191
    wgrow[q] = n * G3_ + (wr >> 6) * BS_ + s0 + (wr & 63);  // global W row
    wcol[q]  = (ol & 127) >> 1;
  }

  f32x4 acc[4][4][2] = {};   // [set][mi][ni]
  float4 st[4][2];           // shared staging buffer: max 4 passes in flight (32 VGPR)

  auto issueA = [&](int t2) {           // fills st[0..3]
#pragma unroll
    for (int p = 0; p < 4; ++p) {
      const float* src = (t2 < 16)
        ? xf + (size_t)(mrow0 + arow[p]) * IN_  + t2 * 64 + acol[p]
        : hf + (size_t)(mrow0 + arow[p]) * HID_ + n * BS_ + (t2 - 16) * 64 + acol[p];
      st[p][0] = *reinterpret_cast<const float4*>(src);
      st[p][1] = *reinterpret_cast<const float4*>(src + 4);
    }
  };
  auto issueW = [&](int t2, int q0) {   // fills st[0..2] with W passes q0..q0+2
#pragma unroll
    for (int j = 0; j < 3; ++j) {
      const int q = q0 + j;
      const float* src = (t2 < 16)
        ? Wih + (size_t)wgrow[q] * IN_ + t2 * 64 + wcol[q]
        : Whh + (size_t)wgrow[q] * BS_ + (t2 - 16) * 64 + wcol[q];
      st[j][0] = *reinterpret_cast<const float4*>(src);
      st[j][1] = *reinterpret_cast<const float4*>(src + 4);
    }
  };
  auto pack8 = [&](const float4& a, const float4& b) {
    union { unsigned u[4]; bf16x8 v; } r;
    r.u[0] = cvtpk(a.x, a.y); r.u[1] = cvtpk(a.z, a.w);
    r.u[2] = cvtpk(b.x, b.y); r.u[3] = cvtpk(b.z, b.w);
    return r.v;
  };
  auto writeA = [&](char* buf) {
#pragma unroll
    for (int p = 0; p < 4; ++p)
      *reinterpret_cast<bf16x8*>(buf + p * 4096 + t * 16) = pack8(st[p][0], st[p][1]);
  };
  auto writeW = [&](char* buf, int q0) {
#pragma unroll
    for (int j = 0; j < 3; ++j)
      *reinterpret_cast<bf16x8*>(buf + 16384 + (q0 + j) * 4096 + t * 16) = pack8(st[j][0], st[j][1]);
  };

  auto loadA = [&](const char* buf, bf16x8 (&af)[2][4]) {
#pragma unroll
    for (int ksub = 0; ksub < 2; ++ksub)
#pragma unroll
      for (int mi = 0; mi < 4; ++mi) {
        int ar  = wm * 64 + mi * 16 + (lane & 15);
        int off = ar * 128 + ksub * 64 + ((lane >> 4) * 16);
        off ^= (ar & 7) << 4;
        af[ksub][mi] = *reinterpret_cast<const bf16x8*>(buf + off);
      }
  };
  auto loadW = [&](const char* buf, int g, bf16x8 (&wf)[2][2]) {
#pragma unroll
    for (int ksub = 0; ksub < 2; ++ksub)
#pragma unroll
      for (int ni = 0; ni < 2; ++ni) {
        int wr  = g * 64 + wn * 32 + ni * 16 + (lane & 15);
        int off = wr * 128 + ksub * 64 + ((lane >> 4) * 16);
        off ^= (wr & 7) << 4;
        wf[ksub][ni] = *reinterpret_cast<const bf16x8*>(buf + 16384 + off);
      }
  };
  auto mfmaSet = [&](auto setc, bf16x8 (&af)[2][4], bf16x8 (&wf)[2][2]) {
    constexpr int set = decltype(setc)::value;
    __builtin_amdgcn_s_setprio(1);
#pragma unroll
    for (int ksub = 0; ksub < 2; ++ksub)
#pragma unroll
      for (int mi = 0; mi < 4; ++mi)
#pragma unroll
        for (int ni = 0; ni < 2; ++ni)
          acc[set][mi][ni] = __builtin_amdgcn_mfma_f32_16x16x32_bf16(
              af[ksub][mi], wf[ksub][ni], acc[set][mi][ni], 0, 0, 0);
    __builtin_amdgcn_s_setprio(0);
  };

  // ---- prologue: stage tile 0 into buf0 ----
  issueA(0);
  writeA((char*)lds[0]);
  issueW(0, 0);
  writeW((char*)lds[0], 0);
  issueW(0, 3);
  writeW((char*)lds[0], 3);
  __syncthreads();

  // ---- 20 K-steps (16 input + 4 hidden), fully unrolled, ONE barrier each ----
#pragma unroll
  for (int tt = 0; tt < 20; ++tt) {
    char* cur = (char*)lds[tt & 1];
    char* oth = (char*)lds[(tt & 1) ^ 1];
    bf16x8 af[2][4], wf[2][2];

    if (tt < 19) issueA(tt + 1);            // T14: issue early (batch 1)
    __builtin_amdgcn_sched_barrier(0);
    loadA(cur, af);
    loadW(cur, 0, wf);
    mfmaSet(ic<0>{}, af, wf);
    __builtin_amdgcn_sched_barrier(0);      // write b1, issue b2
    if (tt < 19) { writeA(oth); issueW(tt + 1, 0); }
    __builtin_amdgcn_sched_barrier(0);
    loadW(cur, 1, wf);
    mfmaSet(ic<1>{}, af, wf);
    __builtin_amdgcn_sched_barrier(0);      // write b2, issue b3
    if (tt < 19) { writeW(oth, 0); issueW(tt + 1, 3); }
    __builtin_amdgcn_sched_barrier(0);
    loadW(cur, 2, wf);
    if (tt < 16) mfmaSet(ic<2>{}, af, wf);
    else         mfmaSet(ic<3>{}, af, wf);
    __builtin_amdgcn_sched_barrier(0);      // write b3
    if (tt < 19) writeW(oth, 3);
    __syncthreads();   // writes to oth visible; reads of cur retired
  }

  // ---- epilogue: gates + output ----
#pragma unroll
  for (int ni = 0; ni < 2; ++ni) {
    int scol = s0 + wn * 32 + ni * 16 + (lane & 15);
    float br_i = b_ih[n * G3_ + 0 * BS_ + scol];
    float bz_i = b_ih[n * G3_ + 1 * BS_ + scol];
    float bn_i = b_ih[n * G3_ + 2 * BS_ + scol];
    float br_h = b_hh[n * G3_ + 0 * BS_ + scol];
    float bz_h = b_hh[n * G3_ + 1 * BS_ + scol];
    float bn_h = b_hh[n * G3_ + 2 * BS_ + scol];
    int gcol = n * BS_ + scol;
#pragma unroll
    for (int mi = 0; mi < 4; ++mi) {
#pragma unroll
      for (int i = 0; i < 4; ++i) {
        int row = mrow0 + wm * 64 + mi * 16 + (lane >> 4) * 4 + i;  // C/D: col=lane&15, row=(lane>>4)*4+reg
        float hprev = hf[(size_t)row * HID_ + gcol];
        float rr = acc[0][mi][ni][i] + br_i + br_h;
        float zz = acc[1][mi][ni][i] + bz_i + bz_h;
        float r  = 1.f / (1.f + __expf(-rr));
        float z  = 1.f / (1.f + __expf(-zz));
        float ng = tanhf(acc[2][mi][ni][i] + bn_i + r * (acc[3][mi][ni][i] + bn_h));
        out[(size_t)row * HID_ + gcol] = (1.f - z) * ng + z * hprev;
      }
    }
  }
}

extern "C" void kernel_launch(void* const* d_in, const int* in_sizes, int n_in,
                              void* d_out, int out_size, void* d_ws, size_t ws_size,
                              hipStream_t stream) {
  const float* x   = (const float*)d_in[0];
  const float* h   = (const float*)d_in[1];
  const float* Wih = (const float*)d_in[2];
  const float* Whh = (const float*)d_in[3];
  const float* bih = (const float*)d_in[4];
  const float* bhh = (const float*)d_in[5];
  float* out = (float*)d_out;
  (void)d_ws; (void)ws_size;

  gru_mfma<<<512, 256, 0, stream>>>(x, h, Wih, Whh, bih, bhh, out);
}